// Round 2
// baseline (104.842 us; speedup 1.0000x reference)
//
#include <hip/hip_runtime.h>
#include <math.h>

#define NQ      4
#define QDEPTH  6
#define TPB     256    // 4 waves/block, 1 sample/thread
#define ROWLEN  64

// ---- fast math helpers (threshold 2.5e-2; these are ~1e-6 accurate) ----
__device__ __forceinline__ float fast_tanh(float x) {
    // tanh(x) = 1 - 2/(exp(2x)+1); exact at +-inf saturation
    float e = __expf(2.0f * x);
    float r = __builtin_amdgcn_rcpf(e + 1.0f);
    return fmaf(-2.0f, r, 1.0f);
}

// ---- 4-qubit real statevector gates, fully register-resident ----
// index i = b0*8 + b1*4 + b2*2 + b3  (wire w <-> bit mask 8>>w)
template<int W>
__device__ __forceinline__ void apply_ry(float st[16], float c, float s) {
    constexpr int M = 8 >> W;
#pragma unroll
    for (int i = 0; i < 16; ++i) {
        if ((i & M) == 0) {
            float a0 = st[i];
            float a1 = st[i | M];
            st[i]     = fmaf(c, a0, -(s * a1));
            st[i | M] = fmaf(s, a0,  (c * a1));
        }
    }
}

template<int C, int T>
__device__ __forceinline__ void apply_cnot(float st[16]) {
    constexpr int MC = 8 >> C;
    constexpr int MT = 8 >> T;
#pragma unroll
    for (int i = 0; i < 16; ++i) {
        if ((i & MC) != 0 && (i & MT) == 0) {
            float tmp = st[i];
            st[i] = st[i | MT];
            st[i | MT] = tmp;
        }
    }
}

__global__ __launch_bounds__(TPB, 4) void dqnet_kernel(
    const float* __restrict__ inp,     // (B, 64)
    const float* __restrict__ pre_w,   // (4, 64)
    const float* __restrict__ pre_b,   // (4,)
    const float* __restrict__ qp,      // (24,)  = (6,4) row-major
    const float* __restrict__ post_w,  // (1, 4)
    const float* __restrict__ post_b,  // (1,)
    float* __restrict__ out)           // (B,)
{
    __shared__ float cw[QDEPTH * NQ];
    __shared__ float sw[QDEPTH * NQ];
    __shared__ float gg[16];

    const int t = threadIdx.x;

    // per-block constants: weight-angle cos/sin and folded sign*post_w coeffs
    if (t < QDEPTH * NQ) {
        float h = 0.5f * qp[t];
        cw[t] = __cosf(h);
        sw[t] = __sinf(h);
    } else if (t >= 32 && t < 48) {
        int i = t - 32;
        float v = 0.0f;
#pragma unroll
        for (int w = 0; w < NQ; ++w) {
            float p = post_w[w];
            v += ((i >> (3 - w)) & 1) ? -p : p;
        }
        gg[i] = v;
    }
    __syncthreads();   // only 256 B of LDS written; cheap drain (no vmem in flight yet)

    // ---- pre-layer: each thread reads its own 256 B row, 16x float4 ----
    // Per-instr lane stride is 256 B; each 64 B line is consumed by one lane
    // over 4 consecutive i's, wave footprint 16 KB lives in L1. Weight
    // indices are wave-uniform -> s_load into SGPRs.
    const size_t row = (size_t)blockIdx.x * TPB + t;
    const float4* rp  = (const float4*)(inp + row * ROWLEN);
    const float4* pw4 = (const float4*)pre_w;

    float acc0 = pre_b[0], acc1 = pre_b[1], acc2 = pre_b[2], acc3 = pre_b[3];
#pragma unroll
    for (int i = 0; i < 16; ++i) {
        float4 x  = rp[i];
        float4 w0 = pw4[i];
        float4 w1 = pw4[16 + i];
        float4 w2 = pw4[32 + i];
        float4 w3 = pw4[48 + i];
        acc0 = fmaf(x.x, w0.x, acc0); acc0 = fmaf(x.y, w0.y, acc0);
        acc0 = fmaf(x.z, w0.z, acc0); acc0 = fmaf(x.w, w0.w, acc0);
        acc1 = fmaf(x.x, w1.x, acc1); acc1 = fmaf(x.y, w1.y, acc1);
        acc1 = fmaf(x.z, w1.z, acc1); acc1 = fmaf(x.w, w1.w, acc1);
        acc2 = fmaf(x.x, w2.x, acc2); acc2 = fmaf(x.y, w2.y, acc2);
        acc2 = fmaf(x.z, w2.z, acc2); acc2 = fmaf(x.w, w2.w, acc2);
        acc3 = fmaf(x.x, w3.x, acc3); acc3 = fmaf(x.y, w3.y, acc3);
        acc3 = fmaf(x.z, w3.z, acc3); acc3 = fmaf(x.w, w3.w, acc3);
    }

    // ---- q_in half-angles: tanh(pre)*pi/4 ----
    const float QK = 0.78539816339744831f;   // pi/4
    float h0 = fast_tanh(acc0) * QK;
    float h1 = fast_tanh(acc1) * QK;
    float h2 = fast_tanh(acc2) * QK;
    float h3 = fast_tanh(acc3) * QK;
    float c0 = __cosf(h0), s0 = __sinf(h0);
    float c1 = __cosf(h1), s1 = __sinf(h1);
    float c2 = __cosf(h2), s2 = __sinf(h2);
    float c3 = __cosf(h3), s3 = __sinf(h3);

    // ---- initial state: RY_w(q_in) applied to |++++> is a product state ----
    const float R = 0.70710678118654752f;    // 1/sqrt(2)
    float u0 = (c0 - s0) * R, v0 = (c0 + s0) * R;
    float u1 = (c1 - s1) * R, v1 = (c1 + s1) * R;
    float u2 = (c2 - s2) * R, v2 = (c2 + s2) * R;
    float u3 = (c3 - s3) * R, v3 = (c3 + s3) * R;

    float p00 = u0 * u1, p01 = u0 * v1, p10 = v0 * u1, p11 = v0 * v1; // (b0,b1)
    float q00 = u2 * u3, q01 = u2 * v3, q10 = v2 * u3, q11 = v2 * v3; // (b2,b3)

    float st[16];
    st[ 0] = p00 * q00; st[ 1] = p00 * q01; st[ 2] = p00 * q10; st[ 3] = p00 * q11;
    st[ 4] = p01 * q00; st[ 5] = p01 * q01; st[ 6] = p01 * q10; st[ 7] = p01 * q11;
    st[ 8] = p10 * q00; st[ 9] = p10 * q01; st[10] = p10 * q10; st[11] = p10 * q11;
    st[12] = p11 * q00; st[13] = p11 * q01; st[14] = p11 * q10; st[15] = p11 * q11;

    // ---- 6 entangling + RY(weight) layers ----
#pragma unroll
    for (int k = 0; k < QDEPTH; ++k) {
        apply_cnot<0, 1>(st);
        apply_cnot<2, 3>(st);
        apply_cnot<1, 2>(st);
        apply_ry<0>(st, cw[k * 4 + 0], sw[k * 4 + 0]);
        apply_ry<1>(st, cw[k * 4 + 1], sw[k * 4 + 1]);
        apply_ry<2>(st, cw[k * 4 + 2], sw[k * 4 + 2]);
        apply_ry<3>(st, cw[k * 4 + 3], sw[k * 4 + 3]);
    }

    // ---- fused expz + post-layer: out = sum_i st[i]^2 * g[i] + post_b ----
    float r = post_b[0];
#pragma unroll
    for (int i = 0; i < 16; ++i)
        r = fmaf(st[i] * st[i], gg[i], r);

    out[row] = r;
}

extern "C" void kernel_launch(void* const* d_in, const int* in_sizes, int n_in,
                              void* d_out, int out_size, void* d_ws, size_t ws_size,
                              hipStream_t stream) {
    const float* inp    = (const float*)d_in[0];
    const float* pre_w  = (const float*)d_in[1];
    const float* pre_b  = (const float*)d_in[2];
    const float* qp     = (const float*)d_in[3];
    const float* post_w = (const float*)d_in[4];
    const float* post_b = (const float*)d_in[5];
    float* out = (float*)d_out;

    int n = in_sizes[0] / ROWLEN;          // batch size (262144)
    int grid = n / TPB;                    // 1024 blocks
    dqnet_kernel<<<grid, TPB, 0, stream>>>(inp, pre_w, pre_b, qp, post_w, post_b, out);
}

// Round 3
// 101.781 us; speedup vs baseline: 1.0301x; 1.0301x over previous
//
#include <hip/hip_runtime.h>
#include <math.h>

#define NQ      4
#define QDEPTH  6
#define TPB     256    // 4 waves/block, 1 sample/thread
#define ROWLEN  64

// ---- fast math helpers (threshold 2.5e-2; these are ~1e-6 accurate) ----
__device__ __forceinline__ float fast_tanh(float x) {
    // tanh(x) = 1 - 2/(exp(2x)+1); exact at +-inf saturation
    float e = __expf(2.0f * x);
    float r = __builtin_amdgcn_rcpf(e + 1.0f);
    return fmaf(-2.0f, r, 1.0f);
}

// ---- 4-qubit real statevector gates, fully register-resident ----
// index i = b0*8 + b1*4 + b2*2 + b3  (wire w <-> bit mask 8>>w)
template<int W>
__device__ __forceinline__ void apply_ry(float st[16], float c, float s) {
    constexpr int M = 8 >> W;
#pragma unroll
    for (int i = 0; i < 16; ++i) {
        if ((i & M) == 0) {
            float a0 = st[i];
            float a1 = st[i | M];
            st[i]     = fmaf(c, a0, -(s * a1));
            st[i | M] = fmaf(s, a0,  (c * a1));
        }
    }
}

template<int C, int T>
__device__ __forceinline__ void apply_cnot(float st[16]) {
    constexpr int MC = 8 >> C;
    constexpr int MT = 8 >> T;
#pragma unroll
    for (int i = 0; i < 16; ++i) {
        if ((i & MC) != 0 && (i & MT) == 0) {
            float tmp = st[i];
            st[i] = st[i | MT];
            st[i | MT] = tmp;
        }
    }
}

__global__ __launch_bounds__(TPB, 4) void dqnet_kernel(
    const float* __restrict__ inp,     // (B, 64)
    const float* __restrict__ pre_w,   // (4, 64)
    const float* __restrict__ pre_b,   // (4,)
    const float* __restrict__ qp,      // (24,)  = (6,4) row-major
    const float* __restrict__ post_w,  // (1, 4)
    const float* __restrict__ post_b,  // (1,)
    float* __restrict__ out)           // (B,)
{
    // Per-wave private 8 KB transpose quadrant (64 rows x 32 cols fp32),
    // XOR-swizzled: float4 (row r, chunk c) lives at slot r*8 + (c ^ (r&7)).
    // Both write (coalesced-load order) and read (row-major order) patterns
    // land uniformly at 8 words/bank = b128 conflict floor.
    __shared__ float4 tile[4 * 512];           // 32 KB
    __shared__ float cw[QDEPTH * NQ];
    __shared__ float sw[QDEPTH * NQ];
    __shared__ float gg[16];

    const int t = threadIdx.x;

    // per-block constants: weight-angle cos/sin and folded sign*post_w coeffs
    if (t < QDEPTH * NQ) {
        float h = 0.5f * qp[t];
        cw[t] = __cosf(h);
        sw[t] = __sinf(h);
    } else if (t >= 32 && t < 48) {
        int i = t - 32;
        float v = 0.0f;
#pragma unroll
        for (int w = 0; w < NQ; ++w) {
            float p = post_w[w];
            v += ((i >> (3 - w)) & 1) ? -p : p;
        }
        gg[i] = v;
    }
    __syncthreads();   // constants only; no vmem in flight yet

    const int wave = t >> 6;
    const int lane = t & 63;
    const size_t wrow0 = (size_t)blockIdx.x * TPB + wave * 64;  // wave's first row
    const float4* gp = (const float4*)(inp + wrow0 * ROWLEN);   // row r chunk k at gp[r*16+k]
    float4* wt = &tile[wave * 512];
    const float4* pw4 = (const float4*)pre_w;

    // ---- pass 0 loads (cols 0..31), fully coalesced: 8 x 1KB/wave ----
    float4 x0[8], x1[8];
#pragma unroll
    for (int j = 0; j < 8; ++j) {
        int idx = j * 64 + lane;
        int rw = idx >> 3, c = idx & 7;       // row-in-wave, half-row chunk
        x0[j] = gp[rw * 16 + c];
    }
    // write pass 0 into swizzled LDS
#pragma unroll
    for (int j = 0; j < 8; ++j) {
        int idx = j * 64 + lane;
        int rw = idx >> 3, c = idx & 7;
        wt[rw * 8 + (c ^ (rw & 7))] = x0[j];
    }
    // issue pass 1 loads (cols 32..63) now so HBM latency overlaps pass-0 math
#pragma unroll
    for (int j = 0; j < 8; ++j) {
        int idx = j * 64 + lane;
        int rw = idx >> 3, c = idx & 7;
        x1[j] = gp[rw * 16 + 8 + c];
    }

    // ---- pass 0 matvec: my row = lane, cols 0..31 (weights via s_load) ----
    float acc0 = pre_b[0], acc1 = pre_b[1], acc2 = pre_b[2], acc3 = pre_b[3];
#pragma unroll
    for (int i = 0; i < 8; ++i) {
        float4 x  = wt[lane * 8 + (i ^ (lane & 7))];
        float4 w0 = pw4[0 * 16 + i];
        float4 w1 = pw4[1 * 16 + i];
        float4 w2 = pw4[2 * 16 + i];
        float4 w3 = pw4[3 * 16 + i];
        acc0 = fmaf(x.x, w0.x, acc0); acc0 = fmaf(x.y, w0.y, acc0);
        acc0 = fmaf(x.z, w0.z, acc0); acc0 = fmaf(x.w, w0.w, acc0);
        acc1 = fmaf(x.x, w1.x, acc1); acc1 = fmaf(x.y, w1.y, acc1);
        acc1 = fmaf(x.z, w1.z, acc1); acc1 = fmaf(x.w, w1.w, acc1);
        acc2 = fmaf(x.x, w2.x, acc2); acc2 = fmaf(x.y, w2.y, acc2);
        acc2 = fmaf(x.z, w2.z, acc2); acc2 = fmaf(x.w, w2.w, acc2);
        acc3 = fmaf(x.x, w3.x, acc3); acc3 = fmaf(x.y, w3.y, acc3);
        acc3 = fmaf(x.z, w3.z, acc3); acc3 = fmaf(x.w, w3.w, acc3);
    }

    // ---- write + read pass 1 (same slots; in-order DS pipe makes WAR safe) ----
#pragma unroll
    for (int j = 0; j < 8; ++j) {
        int idx = j * 64 + lane;
        int rw = idx >> 3, c = idx & 7;
        wt[rw * 8 + (c ^ (rw & 7))] = x1[j];
    }
#pragma unroll
    for (int i = 0; i < 8; ++i) {
        float4 x  = wt[lane * 8 + (i ^ (lane & 7))];
        float4 w0 = pw4[0 * 16 + 8 + i];
        float4 w1 = pw4[1 * 16 + 8 + i];
        float4 w2 = pw4[2 * 16 + 8 + i];
        float4 w3 = pw4[3 * 16 + 8 + i];
        acc0 = fmaf(x.x, w0.x, acc0); acc0 = fmaf(x.y, w0.y, acc0);
        acc0 = fmaf(x.z, w0.z, acc0); acc0 = fmaf(x.w, w0.w, acc0);
        acc1 = fmaf(x.x, w1.x, acc1); acc1 = fmaf(x.y, w1.y, acc1);
        acc1 = fmaf(x.z, w1.z, acc1); acc1 = fmaf(x.w, w1.w, acc1);
        acc2 = fmaf(x.x, w2.x, acc2); acc2 = fmaf(x.y, w2.y, acc2);
        acc2 = fmaf(x.z, w2.z, acc2); acc2 = fmaf(x.w, w2.w, acc2);
        acc3 = fmaf(x.x, w3.x, acc3); acc3 = fmaf(x.y, w3.y, acc3);
        acc3 = fmaf(x.z, w3.z, acc3); acc3 = fmaf(x.w, w3.w, acc3);
    }

    // ---- q_in half-angles: tanh(pre)*pi/4 ----
    const float QK = 0.78539816339744831f;   // pi/4
    float h0 = fast_tanh(acc0) * QK;
    float h1 = fast_tanh(acc1) * QK;
    float h2 = fast_tanh(acc2) * QK;
    float h3 = fast_tanh(acc3) * QK;
    float c0 = __cosf(h0), s0 = __sinf(h0);
    float c1 = __cosf(h1), s1 = __sinf(h1);
    float c2 = __cosf(h2), s2 = __sinf(h2);
    float c3 = __cosf(h3), s3 = __sinf(h3);

    // ---- initial state: RY_w(q_in) applied to |++++> is a product state ----
    const float R = 0.70710678118654752f;    // 1/sqrt(2)
    float u0 = (c0 - s0) * R, v0 = (c0 + s0) * R;
    float u1 = (c1 - s1) * R, v1 = (c1 + s1) * R;
    float u2 = (c2 - s2) * R, v2 = (c2 + s2) * R;
    float u3 = (c3 - s3) * R, v3 = (c3 + s3) * R;

    float p00 = u0 * u1, p01 = u0 * v1, p10 = v0 * u1, p11 = v0 * v1; // (b0,b1)
    float q00 = u2 * u3, q01 = u2 * v3, q10 = v2 * u3, q11 = v2 * v3; // (b2,b3)

    float st[16];
    st[ 0] = p00 * q00; st[ 1] = p00 * q01; st[ 2] = p00 * q10; st[ 3] = p00 * q11;
    st[ 4] = p01 * q00; st[ 5] = p01 * q01; st[ 6] = p01 * q10; st[ 7] = p01 * q11;
    st[ 8] = p10 * q00; st[ 9] = p10 * q01; st[10] = p10 * q10; st[11] = p10 * q11;
    st[12] = p11 * q00; st[13] = p11 * q01; st[14] = p11 * q10; st[15] = p11 * q11;

    // ---- 6 entangling + RY(weight) layers ----
#pragma unroll
    for (int k = 0; k < QDEPTH; ++k) {
        apply_cnot<0, 1>(st);
        apply_cnot<2, 3>(st);
        apply_cnot<1, 2>(st);
        apply_ry<0>(st, cw[k * 4 + 0], sw[k * 4 + 0]);
        apply_ry<1>(st, cw[k * 4 + 1], sw[k * 4 + 1]);
        apply_ry<2>(st, cw[k * 4 + 2], sw[k * 4 + 2]);
        apply_ry<3>(st, cw[k * 4 + 3], sw[k * 4 + 3]);
    }

    // ---- fused expz + post-layer: out = sum_i st[i]^2 * g[i] + post_b ----
    float r = post_b[0];
#pragma unroll
    for (int i = 0; i < 16; ++i)
        r = fmaf(st[i] * st[i], gg[i], r);

    out[wrow0 + lane] = r;
}

extern "C" void kernel_launch(void* const* d_in, const int* in_sizes, int n_in,
                              void* d_out, int out_size, void* d_ws, size_t ws_size,
                              hipStream_t stream) {
    const float* inp    = (const float*)d_in[0];
    const float* pre_w  = (const float*)d_in[1];
    const float* pre_b  = (const float*)d_in[2];
    const float* qp     = (const float*)d_in[3];
    const float* post_w = (const float*)d_in[4];
    const float* post_b = (const float*)d_in[5];
    float* out = (float*)d_out;

    int n = in_sizes[0] / ROWLEN;          // batch size (262144)
    int grid = n / TPB;                    // 1024 blocks
    dqnet_kernel<<<grid, TPB, 0, stream>>>(inp, pre_w, pre_b, qp, post_w, post_b, out);
}